// Round 6
// baseline (429.910 us; speedup 1.0000x reference)
//
#include <hip/hip_runtime.h>
#include <hip/hip_fp16.h>

#define BB 512
#define TT 2048

typedef _Float16 half2v __attribute__((ext_vector_type(2)));

// ---------- fast math helpers ----------
__device__ __forceinline__ float fexp2(float x){ return __builtin_amdgcn_exp2f(x); }
__device__ __forceinline__ float frcp(float x){ return __builtin_amdgcn_rcpf(x); }
__device__ __forceinline__ float sigm(float x){ return frcp(1.f + fexp2(-1.4426950408889634f*x)); }
__device__ __forceinline__ float tanhfast(float x){ return 1.f - 2.f*frcp(1.f + fexp2(2.8853900817779268f*x)); }

#define QB(v, ctrl) __int_as_float(__builtin_amdgcn_mov_dpp(__float_as_int(v), (ctrl), 0xF, 0xF, true))
#define RL(v, l)    __builtin_amdgcn_readlane((v), (l))

// pack two f32 -> f16x2 as raw uint (cvt_pkrtz returns __fp16 vec; bit_cast it)
__device__ __forceinline__ unsigned pkrtz_u(float a, float b){
  return __builtin_bit_cast(unsigned, __builtin_amdgcn_cvt_pkrtz(a, b));
}

__device__ __forceinline__ float fdot2(half2v a, half2v b, float c){
#if __has_builtin(__builtin_amdgcn_fdot2)
  return __builtin_amdgcn_fdot2(a, b, c, false);
#else
  float r = fmaf((float)a.x, (float)b.x, c);
  return fmaf((float)a.y, (float)b.y, r);
#endif
}

// ---------- fused kernel: per-block xg prologue + recurrence ----------
// xg layout: [b][tg][e][u] f16, e = q*13+j (row 16B), u = t&7; row stride 832B.
// lane 4j+q owns gate q of hidden unit j.
__global__ __launch_bounds__(64, 1) void k_rec5(const float* __restrict__ x,
                                                const float* __restrict__ Wih,
                                                const float* __restrict__ Whh,
                                                const float* __restrict__ bih,
                                                const float* __restrict__ bhh,
                                                unsigned short* __restrict__ xg,
                                                unsigned short* __restrict__ hs)
{
  const int lane = threadIdx.x;
  const int b    = blockIdx.x;
  const int q    = lane & 3;
  const int j    = lane >> 2;             // 0..15 (13..15 padding)
  const int jc   = (j < 13) ? j : 12;
  const int e    = q*13 + jc;

  const float kq = (q==2) ? -2.8853900817779268f : -1.4426950408889634f;

  // W_hh row, pre-scaled by k_q, packed f16 pairs (7 VGPRs)
  unsigned wp[7];
  {
    float wt[14];
    #pragma unroll
    for (int k=0;k<13;k++) wt[k] = Whh[e*13 + k]*kq;
    wt[13] = 0.f;
    #pragma unroll
    for (int m=0;m<7;m++) wp[m] = pkrtz_u(wt[2*m], wt[2*m+1]);
  }

  char* xgb = (char*)xg + (size_t)b*256*832;      // this block's xg region

  // ---- prologue: compute this batch's input projections ----
  {
    const float* xrow = x + (size_t)b*TT*13;
    for (int chunk=0; chunk<32; ++chunk){
      const int t = (chunk<<6) + lane;
      const float* p = xrow + t*13;
      float xv[13];
      #pragma unroll
      for (int k=0;k<13;k++) xv[k] = p[k];
      unsigned short* ob = (unsigned short*)(xgb + (size_t)(t>>3)*832) + (t&7);
      #pragma unroll 4
      for (int g=0; g<52; ++g){
        float acc = bih[g] + bhh[g];
        #pragma unroll
        for (int k=0;k<13;k++) acc = fmaf(Wih[g*13+k], xv[k], acc);
        acc *= (g>=26 && g<39) ? -2.8853900817779268f : -1.4426950408889634f;
        ob[g*8] = __half_as_ushort(__float2half(acc));
      }
    }
    __builtin_amdgcn_s_waitcnt(0);   // drain stores before reading them back
    __threadfence_block();
  }

  const char* gbase = (const char*)xgb + (size_t)e*16;

  float h = 0.f, c_ = 0.f;                // c_ carries -2*log2e*c
  int hp0=0,hp1=0,hp2=0,hp3=0,hp4=0,hp5=0,hp6=0;   // packed f16 h pairs (SGPR-held)

  const bool wr = (q==0) && (j<13);
  uint4* hsrow = (uint4*)(hs + ((size_t)b*13 + jc)*TT);
  float hprev = 0.f;
  unsigned pk0=0u, pk1=0u, pk2=0u, pk3=0u;

#define H2(v_) __builtin_bit_cast(half2v, (unsigned)(v_))

#define STEP(xv_, u_) do {                                                    \
    float dA = fdot2(H2(wp[0]), H2(hp0), (xv_));                              \
    dA = fdot2(H2(wp[1]), H2(hp1), dA);                                       \
    dA = fdot2(H2(wp[2]), H2(hp2), dA);                                       \
    dA = fdot2(H2(wp[3]), H2(hp3), dA);                                       \
    float dB = fdot2(H2(wp[4]), H2(hp4), 0.f);                                \
    dB = fdot2(H2(wp[5]), H2(hp5), dB);                                       \
    dB = fdot2(H2(wp[6]), H2(hp6), dB);                                       \
    float s  = dA + dB;                                                       \
    float r  = frcp(1.f + fexp2(s));                                          \
    float gfb = QB(r, 0x55);                                                  \
    float gtb = QB(r, 0xAA);                                                  \
    float gob = QB(r, 0xFF);                                                  \
    float ggb = fmaf(-5.7707801635558536f, gtb, 2.8853900817779268f);         \
    c_ = fmaf(gfb, c_, r*ggb);                                                \
    float r2 = frcp(1.f + fexp2(c_));                                         \
    float go2 = gob + gob;                                                    \
    h = fmaf(go2, r2, -gob);                                                  \
    if ((u_) & 1) {                                                           \
      unsigned pp = pkrtz_u(hprev, h);                                        \
      if ((u_)==1) pk0=pp; else if ((u_)==3) pk1=pp;                          \
      else if ((u_)==5) pk2=pp; else pk3=pp;                                  \
    } else hprev = h;                                                         \
    float hnb = __int_as_float(__builtin_amdgcn_mov_dpp(__float_as_int(h),    \
                                 0x104, 0xF, 0xF, true)); /* row_shl:4 */     \
    int pki = (int)pkrtz_u(h, hnb);                                           \
    hp0 = RL(pki, 0);  hp1 = RL(pki, 8);  hp2 = RL(pki, 16);                  \
    hp3 = RL(pki, 24); hp4 = RL(pki, 32); hp5 = RL(pki, 40);                  \
    hp6 = RL(pki, 48);                                                        \
  } while(0)

#define XLO(w_) (float)(__builtin_bit_cast(half2v, (w_)).x)
#define XHI(w_) (float)(__builtin_bit_cast(half2v, (w_)).y)

#define STEP8(Q) do {                                                         \
    STEP(XLO(Q.x), 0); STEP(XHI(Q.x), 1);                                     \
    STEP(XLO(Q.y), 2); STEP(XHI(Q.y), 3);                                     \
    STEP(XLO(Q.z), 4); STEP(XHI(Q.z), 5);                                     \
    STEP(XLO(Q.w), 6); STEP(XHI(Q.w), 7);                                     \
    if (wr) *hsrow = make_uint4(pk0, pk1, pk2, pk3);                          \
    ++hsrow;                                                                  \
  } while(0)

  uint4 q0 = *(const uint4*)(gbase);
  uint4 q1 = *(const uint4*)(gbase + 832);
  uint4 q2 = *(const uint4*)(gbase + 2*832);
  uint4 q3 = *(const uint4*)(gbase + 3*832);

  for (int i=0; i<63; ++i){
    const char* pn = gbase + (size_t)(4*i+4)*832;
    uint4 c0 = q0; q0 = *(const uint4*)(pn);
    STEP8(c0);
    uint4 c1 = q1; q1 = *(const uint4*)(pn + 832);
    STEP8(c1);
    uint4 c2 = q2; q2 = *(const uint4*)(pn + 2*832);
    STEP8(c2);
    uint4 c3 = q3; q3 = *(const uint4*)(pn + 3*832);
    STEP8(c3);
  }
  STEP8(q0); STEP8(q1); STEP8(q2); STEP8(q3);

#undef STEP8
#undef STEP
#undef XLO
#undef XHI
#undef H2
}

// ---------- pass 3: out[b][t] = sigmoid( fc_b + sum_j fc_w[j]*hs[b][j][t] ) ----------
__global__ __launch_bounds__(256) void k_out2(const unsigned short* __restrict__ hs,
                                              const float* __restrict__ fcw,
                                              const float* __restrict__ fcb,
                                              float* __restrict__ out)
{
  int idx = blockIdx.x*256 + threadIdx.x;   // over B*T
  int b   = idx >> 11;
  int t   = idx & 2047;
  const unsigned short* row = hs + (size_t)b*13*TT + t;
  float acc = fcb[0];
  #pragma unroll
  for (int j=0;j<13;j++){
    float hj = (float)__builtin_bit_cast(_Float16, row[(size_t)j*TT]);
    acc = fmaf(fcw[j], hj, acc);
  }
  out[idx] = sigm(acc);
}

// ---------- fallback (no workspace) ----------
__global__ __launch_bounds__(64) void k_rec_fb(
    const float* __restrict__ x,   const float* __restrict__ Whh,
    const float* __restrict__ Wih, const float* __restrict__ bih, const float* __restrict__ bhh,
    const float* __restrict__ fcw, const float* __restrict__ fcb,
    float* __restrict__ out)
{
  const int lane = threadIdx.x;
  const int c    = lane >> 4;
  const int j    = lane & 15;
  const int b    = blockIdx.x*4 + c;
  const bool act = (j < 13);
  const int jj   = act ? j : 0;

  float whh[4][13], wih[4][13], bias[4];
  #pragma unroll
  for (int q=0;q<4;q++){
    #pragma unroll
    for (int k=0;k<13;k++){
      float w1 = Whh[(q*13+jj)*13 + k];
      float w2 = Wih[(q*13+jj)*13 + k];
      whh[q][k] = act ? w1 : 0.f;
      wih[q][k] = act ? w2 : 0.f;
    }
    bias[q] = bih[q*13+jj] + bhh[q*13+jj];
  }
  const float fcwj = act ? fcw[jj] : 0.f;
  const float fcb0 = fcb[0];

  const float* xpf = x + (size_t)b*(TT*13) + jj;
  float* op = out + (size_t)b*TT;

  float h = 0.f, cs = 0.f;
  float xsc = *xpf;

  for (int t=0; t<TT; ++t){
    float xscn = 0.f;
    if (t+1 < TT) { xpf += 13; xscn = *xpf; }

    float hb[13], xb[13];
    {
      int hbits = __float_as_int(h);
      int xbits = __float_as_int(xsc);
      #define HB(k) hb[k] = __int_as_float(__builtin_amdgcn_ds_swizzle(hbits, ((k)<<5)|0x10)); \
                    xb[k] = __int_as_float(__builtin_amdgcn_ds_swizzle(xbits, ((k)<<5)|0x10));
      HB(0) HB(1) HB(2) HB(3) HB(4) HB(5) HB(6) HB(7) HB(8) HB(9) HB(10) HB(11) HB(12)
      #undef HB
    }
    float a0 = bias[0], a1 = bias[1], a2 = bias[2], a3 = bias[3];
    #pragma unroll
    for (int k=0;k<13;k++){
      float xk = xb[k], hk = hb[k];
      a0 += wih[0][k]*xk + whh[0][k]*hk;
      a1 += wih[1][k]*xk + whh[1][k]*hk;
      a2 += wih[2][k]*xk + whh[2][k]*hk;
      a3 += wih[3][k]*xk + whh[3][k]*hk;
    }
    float ig = sigm(a0), fg = sigm(a1), gg = tanhfast(a2), og = sigm(a3);
    cs = fg*cs + ig*gg;
    h  = og * tanhfast(cs);

    float p = act ? fcwj*h : 0.f;
    #define RED(m) p += __int_as_float(__builtin_amdgcn_ds_swizzle(__float_as_int(p), ((m)<<10)|0x1F));
    RED(1) RED(2) RED(4) RED(8)
    #undef RED
    if (j == 0) op[t] = sigm(p + fcb0);
    xsc = xscn;
  }
}

extern "C" void kernel_launch(void* const* d_in, const int* in_sizes, int n_in,
                              void* d_out, int out_size, void* d_ws, size_t ws_size,
                              hipStream_t stream)
{
  const float* x   = (const float*)d_in[0];
  const float* Wih = (const float*)d_in[1];
  const float* Whh = (const float*)d_in[2];
  const float* bih = (const float*)d_in[3];
  const float* bhh = (const float*)d_in[4];
  const float* fcw = (const float*)d_in[5];
  const float* fcb = (const float*)d_in[6];
  float* out = (float*)d_out;

  const size_t XG_BYTES = (size_t)BB*256*832;     // 109,051,904  f16 [b][tg][52][8]
  const size_t HS_BYTES = (size_t)BB*13*TT*2;     //  27,262,976  f16 [b][j][t]

  if (ws_size >= XG_BYTES + HS_BYTES){
    unsigned short* xg = (unsigned short*)d_ws;
    unsigned short* hs = (unsigned short*)((char*)d_ws + XG_BYTES);
    k_rec5<<<dim3(BB), dim3(64), 0, stream>>>(x, Wih, Whh, bih, bhh, xg, hs);
    k_out2<<<dim3((BB*TT)/256), dim3(256), 0, stream>>>(hs, fcw, fcb, out);
  } else {
    k_rec_fb<<<dim3(BB/4), dim3(64), 0, stream>>>(x, Whh, Wih, bih, bhh, fcw, fcb, out);
  }
}

// Round 7
// 323.857 us; speedup vs baseline: 1.3275x; 1.3275x over previous
//
#include <hip/hip_runtime.h>
#include <hip/hip_fp16.h>

#define BB 512
#define TT 2048

typedef _Float16 half2v __attribute__((ext_vector_type(2)));

// ---------- fast math helpers ----------
__device__ __forceinline__ float fexp2(float x){ return __builtin_amdgcn_exp2f(x); }
__device__ __forceinline__ float frcp(float x){ return __builtin_amdgcn_rcpf(x); }
__device__ __forceinline__ float sigm(float x){ return frcp(1.f + fexp2(-1.4426950408889634f*x)); }
__device__ __forceinline__ float tanhfast(float x){ return 1.f - 2.f*frcp(1.f + fexp2(2.8853900817779268f*x)); }

#define QB(v, ctrl) __int_as_float(__builtin_amdgcn_mov_dpp(__float_as_int(v), (ctrl), 0xF, 0xF, true))
#define RL(v, l)    __builtin_amdgcn_readlane((v), (l))

// ---------- pass 1: xg[b][tg][e][u] = f16( -k_q * preact ), 53 rows ----------
// rows 0..51: e = q*13+j, preact = x·W_ih^T + b_ih + b_hh, k_q = 2*log2e for q==2 else log2e
// row 52:     constant -log2e * fc_b  (FC fusion row)
// u = t&7; row stride 16B; tg stride 848B.
__global__ __launch_bounds__(256) void k_xg3(const float* __restrict__ x,
                                             const float* __restrict__ Wih,
                                             const float* __restrict__ bih,
                                             const float* __restrict__ bhh,
                                             const float* __restrict__ fcb,
                                             unsigned* __restrict__ xg_u)
{
  __shared__ float    xs[13*256];
  __shared__ unsigned ot[32*212];      // 32 tg x 424 ushorts (53 rows x 8) = 848B/tg
  const int tid = threadIdx.x;
  const int b   = blockIdx.x >> 3;
  const int t0  = (blockIdx.x & 7) << 8;

  const float* xsrc = x + ((size_t)b*TT + t0)*13;
  #pragma unroll
  for (int it=0; it<13; ++it) xs[tid + it*256] = xsrc[tid + it*256];
  __syncthreads();

  float xv[13];
  #pragma unroll
  for (int k=0;k<13;k++) xv[k] = xs[tid*13+k];

  const int tgl = tid >> 3, u = tid & 7;
  unsigned short* otp = (unsigned short*)ot;
  #pragma unroll 2
  for (int g=0; g<52; ++g){            // g = q*13+j; q==2 <=> 26<=g<39
    float acc = bih[g] + bhh[g];
    #pragma unroll
    for (int k=0;k<13;k++) acc = fmaf(Wih[g*13+k], xv[k], acc);
    const float sc = (g>=26 && g<39) ? -2.8853900817779268f : -1.4426950408889634f;
    otp[tgl*424 + g*8 + u] = __half_as_ushort(__float2half(acc*sc));
  }
  // FC row (52): constant -log2e*fc_b
  otp[tgl*424 + 52*8 + u] =
      __half_as_ushort(__float2half(-1.4426950408889634f * fcb[0]));
  __syncthreads();

  // straight copy: LDS layout == xg layout (53 rows x 8 f16 = 212 uints/tg)
  unsigned* dst = xg_u + (size_t)b*(256*212) + (size_t)(blockIdx.x & 7)*(32*212);
  #pragma unroll
  for (int it=0; it<27; ++it){
    int i2 = tid + it*256;
    if (i2 < 32*212) dst[i2] = ot[i2];
  }
}

// ---------- pass 2: recurrence + fused FC. 1 chain/wave; lane 4j+q = gate q of unit j ----------
// lane 52 rides along computing out[t-1] = sigmoid(fc_b + fc_w·h_{t-1}) using the SAME
// instruction stream (its w = -log2e*fc_w, its xg row = -log2e*fc_b).
__global__ __launch_bounds__(64, 1) void k_rec7(const float* __restrict__ Whh,
                                                const float* __restrict__ fcw,
                                                const float* __restrict__ fcb,
                                                const unsigned short* __restrict__ xg,
                                                float* __restrict__ out)
{
  const int lane = threadIdx.x;
  const int b    = blockIdx.x;
  const int q    = lane & 3;
  const int j    = lane >> 2;             // 0..15 (13..15 padding)
  const int jc   = (j < 13) ? j : 12;
  const int e    = (lane == 52) ? 52 : q*13 + jc;

  const float kq = (q==2) ? -2.8853900817779268f : -1.4426950408889634f;
  const float gm = (q==2) ? -5.7707801635558536f : 1.f;
  const float ga = (q==2) ?  2.8853900817779268f : 0.f;
  const float fcbias = -1.4426950408889634f * fcb[0];

  // weight row: Whh row scaled by k_q; lane 52 takes -log2e*fc_w (its kq is -log2e: q==0)
  const float* wsrc = (lane == 52) ? fcw : (Whh + e*13);
  float w[13];
  #pragma unroll
  for (int k=0;k<13;k++) w[k] = wsrc[k]*kq;

  const char* gbase = (const char*)xg + (size_t)b*(256*848) + (size_t)e*16;

  float h = 0.f, c_ = 0.f;                // c_ carries -2*log2e*c
  float hb0=0,hb1=0,hb2=0,hb3=0,hb4=0,hb5=0,hb6=0,hb7=0,hb8=0,hb9=0,hb10=0,hb11=0,hb12=0;

  float p0=0,p1=0,p2=0,p3=0,p4=0,p5=0,p6=0,p7=0;   // out ring (lane 52's values used)
  float* op = out + (size_t)b*TT;
  bool first = true;

#define CAPTURE(gv_, u_) do {                                                 \
    if ((u_)==1) p0=(gv_); else if ((u_)==2) p1=(gv_);                        \
    else if ((u_)==3) p2=(gv_); else if ((u_)==4) p3=(gv_);                   \
    else if ((u_)==5) p4=(gv_); else if ((u_)==6) p5=(gv_);                   \
    else if ((u_)==7) p6=(gv_);                                               \
    else { p7=(gv_);                                                          \
      if (!first){                                                            \
        if (lane == 52){                                                      \
          float4* o4 = (float4*)op;                                           \
          o4[0] = make_float4(p0,p1,p2,p3);                                   \
          o4[1] = make_float4(p4,p5,p6,p7);                                   \
        }                                                                     \
        op += 8;                                                              \
      }                                                                       \
      first = false;                                                          \
    }                                                                         \
  } while(0)

#define STEP(xv_, u_) do {                                                    \
    float dA = fmaf(w[0], hb0, (xv_));                                        \
    dA = fmaf(w[1], hb1, dA);                                                 \
    dA = fmaf(w[2], hb2, dA);                                                 \
    dA = fmaf(w[3], hb3, dA);                                                 \
    dA = fmaf(w[4], hb4, dA);                                                 \
    float dB = w[5]*hb5;                                                      \
    dB = fmaf(w[6], hb6, dB);                                                 \
    dB = fmaf(w[7], hb7, dB);                                                 \
    dB = fmaf(w[8], hb8, dB);                                                 \
    float dC = w[9]*hb9;                                                      \
    dC = fmaf(w[10], hb10, dC);                                               \
    dC = fmaf(w[11], hb11, dC);                                               \
    dC = fmaf(w[12], hb12, dC);                                               \
    float s  = (dB + dC) + dA;                                                \
    float r  = frcp(1.f + fexp2(s));                                          \
    float g  = fmaf(gm, r, ga);                                               \
    CAPTURE(g, u_);                                                           \
    float ggb = QB(g, 0xAA);                                                  \
    float gfb = QB(g, 0x55);                                                  \
    float gob = QB(g, 0xFF);                                                  \
    float go2 = gob + gob;                                                    \
    c_ = fmaf(gfb, c_, g*ggb);                                                \
    float r2 = frcp(1.f + fexp2(c_));                                         \
    h = fmaf(go2, r2, -gob);                                                  \
    int hv_ = __float_as_int(h);                                              \
    hb0  = __int_as_float(RL(hv_, 0));                                        \
    hb1  = __int_as_float(RL(hv_, 4));                                        \
    hb2  = __int_as_float(RL(hv_, 8));                                        \
    hb3  = __int_as_float(RL(hv_, 12));                                       \
    hb4  = __int_as_float(RL(hv_, 16));                                       \
    hb5  = __int_as_float(RL(hv_, 20));                                       \
    hb6  = __int_as_float(RL(hv_, 24));                                       \
    hb7  = __int_as_float(RL(hv_, 28));                                       \
    hb8  = __int_as_float(RL(hv_, 32));                                       \
    hb9  = __int_as_float(RL(hv_, 36));                                       \
    hb10 = __int_as_float(RL(hv_, 40));                                       \
    hb11 = __int_as_float(RL(hv_, 44));                                       \
    hb12 = __int_as_float(RL(hv_, 48));                                       \
  } while(0)

#define XLO(w_) (float)(__builtin_bit_cast(half2v, (w_)).x)
#define XHI(w_) (float)(__builtin_bit_cast(half2v, (w_)).y)

#define STEP8(Q) do {                                                         \
    STEP(XLO(Q.x), 0); STEP(XHI(Q.x), 1);                                     \
    STEP(XLO(Q.y), 2); STEP(XHI(Q.y), 3);                                     \
    STEP(XLO(Q.z), 4); STEP(XHI(Q.z), 5);                                     \
    STEP(XLO(Q.w), 6); STEP(XHI(Q.w), 7);                                     \
  } while(0)

  uint4 q0 = *(const uint4*)(gbase);
  uint4 q1 = *(const uint4*)(gbase + 848);
  uint4 q2 = *(const uint4*)(gbase + 2*848);
  uint4 q3 = *(const uint4*)(gbase + 3*848);

  for (int i=0; i<63; ++i){
    const char* pn = gbase + (size_t)(4*i+4)*848;
    uint4 c0 = q0; q0 = *(const uint4*)(pn);
    STEP8(c0);
    uint4 c1 = q1; q1 = *(const uint4*)(pn + 848);
    STEP8(c1);
    uint4 c2 = q2; q2 = *(const uint4*)(pn + 2*848);
    STEP8(c2);
    uint4 c3 = q3; q3 = *(const uint4*)(pn + 3*848);
    STEP8(c3);
  }
  STEP8(q0); STEP8(q1); STEP8(q2); STEP8(q3);

  // epilogue: out[2047] = sigmoid(fc_b + fc_w·h_2047); lane 52 stores p0..p6 + r
  {
    float s = fcbias;
    s = fmaf(w[0],  hb0,  s);
    s = fmaf(w[1],  hb1,  s);
    s = fmaf(w[2],  hb2,  s);
    s = fmaf(w[3],  hb3,  s);
    s = fmaf(w[4],  hb4,  s);
    s = fmaf(w[5],  hb5,  s);
    s = fmaf(w[6],  hb6,  s);
    s = fmaf(w[7],  hb7,  s);
    s = fmaf(w[8],  hb8,  s);
    s = fmaf(w[9],  hb9,  s);
    s = fmaf(w[10], hb10, s);
    s = fmaf(w[11], hb11, s);
    s = fmaf(w[12], hb12, s);
    float r = frcp(1.f + fexp2(s));
    if (lane == 52){
      float4* o4 = (float4*)op;           // op == out + b*TT + 2040 here
      o4[0] = make_float4(p0,p1,p2,p3);
      o4[1] = make_float4(p4,p5,p6,r);
    }
  }

#undef STEP8
#undef STEP
#undef CAPTURE
#undef XLO
#undef XHI
}

// ---------- fallback (no workspace) ----------
__global__ __launch_bounds__(64) void k_rec_fb(
    const float* __restrict__ x,   const float* __restrict__ Whh,
    const float* __restrict__ Wih, const float* __restrict__ bih, const float* __restrict__ bhh,
    const float* __restrict__ fcw, const float* __restrict__ fcb,
    float* __restrict__ out)
{
  const int lane = threadIdx.x;
  const int c    = lane >> 4;
  const int j    = lane & 15;
  const int b    = blockIdx.x*4 + c;
  const bool act = (j < 13);
  const int jj   = act ? j : 0;

  float whh[4][13], wih[4][13], bias[4];
  #pragma unroll
  for (int q=0;q<4;q++){
    #pragma unroll
    for (int k=0;k<13;k++){
      float w1 = Whh[(q*13+jj)*13 + k];
      float w2 = Wih[(q*13+jj)*13 + k];
      whh[q][k] = act ? w1 : 0.f;
      wih[q][k] = act ? w2 : 0.f;
    }
    bias[q] = bih[q*13+jj] + bhh[q*13+jj];
  }
  const float fcwj = act ? fcw[jj] : 0.f;
  const float fcb0 = fcb[0];

  const float* xpf = x + (size_t)b*(TT*13) + jj;
  float* op = out + (size_t)b*TT;

  float h = 0.f, cs = 0.f;
  float xsc = *xpf;

  for (int t=0; t<TT; ++t){
    float xscn = 0.f;
    if (t+1 < TT) { xpf += 13; xscn = *xpf; }

    float hb[13], xb[13];
    {
      int hbits = __float_as_int(h);
      int xbits = __float_as_int(xsc);
      #define HB(k) hb[k] = __int_as_float(__builtin_amdgcn_ds_swizzle(hbits, ((k)<<5)|0x10)); \
                    xb[k] = __int_as_float(__builtin_amdgcn_ds_swizzle(xbits, ((k)<<5)|0x10));
      HB(0) HB(1) HB(2) HB(3) HB(4) HB(5) HB(6) HB(7) HB(8) HB(9) HB(10) HB(11) HB(12)
      #undef HB
    }
    float a0 = bias[0], a1 = bias[1], a2 = bias[2], a3 = bias[3];
    #pragma unroll
    for (int k=0;k<13;k++){
      float xk = xb[k], hk = hb[k];
      a0 += wih[0][k]*xk + whh[0][k]*hk;
      a1 += wih[1][k]*xk + whh[1][k]*hk;
      a2 += wih[2][k]*xk + whh[2][k]*hk;
      a3 += wih[3][k]*xk + whh[3][k]*hk;
    }
    float ig = sigm(a0), fg = sigm(a1), gg = tanhfast(a2), og = sigm(a3);
    cs = fg*cs + ig*gg;
    h  = og * tanhfast(cs);

    float p = act ? fcwj*h : 0.f;
    #define RED(m) p += __int_as_float(__builtin_amdgcn_ds_swizzle(__float_as_int(p), ((m)<<10)|0x1F));
    RED(1) RED(2) RED(4) RED(8)
    #undef RED
    if (j == 0) op[t] = sigm(p + fcb0);
    xsc = xscn;
  }
}

extern "C" void kernel_launch(void* const* d_in, const int* in_sizes, int n_in,
                              void* d_out, int out_size, void* d_ws, size_t ws_size,
                              hipStream_t stream)
{
  const float* x   = (const float*)d_in[0];
  const float* Wih = (const float*)d_in[1];
  const float* Whh = (const float*)d_in[2];
  const float* bih = (const float*)d_in[3];
  const float* bhh = (const float*)d_in[4];
  const float* fcw = (const float*)d_in[5];
  const float* fcb = (const float*)d_in[6];
  float* out = (float*)d_out;

  const size_t XG_BYTES = (size_t)BB*256*848;     // 111,149,056  f16 [b][tg][53][8]

  if (ws_size >= XG_BYTES){
    unsigned* xg = (unsigned*)d_ws;
    k_xg3<<<dim3(BB*8), dim3(256), 0, stream>>>(x, Wih, bih, bhh, fcb, xg);
    k_rec7<<<dim3(BB), dim3(64), 0, stream>>>(Whh, fcw, fcb,
                                              (const unsigned short*)xg, out);
  } else {
    k_rec_fb<<<dim3(BB/4), dim3(64), 0, stream>>>(x, Whh, Wih, bih, bhh, fcw, fcb, out);
  }
}